// Round 1
// baseline (180.165 us; speedup 1.0000x reference)
//
#include <hip/hip_runtime.h>

#define RES 128
#define NSTEPS 320
#define STEP 0.01f
#define ALPHA_THRE 0.01f

__global__ __launch_bounds__(NSTEPS) void nerfacc_sampler_kernel(
    const float* __restrict__ origins,     // [N,3]
    const float* __restrict__ dirs,        // [N,3]
    const float* __restrict__ occs,        // [RES,RES,RES]
    const float* __restrict__ aabb,        // [2,3]
    float* __restrict__ out,               // 7*N*S floats
    int N)
{
    const int r = blockIdx.x;
    const int j = threadIdx.x;

    // ray data (broadcast loads — all lanes same address, cached)
    const float ox = origins[r * 3 + 0];
    const float oy = origins[r * 3 + 1];
    const float oz = origins[r * 3 + 2];
    const float dx = dirs[r * 3 + 0];
    const float dy = dirs[r * 3 + 1];
    const float dz = dirs[r * 3 + 2];
    const float lx = aabb[0], ly = aabb[1], lz = aabb[2];
    const float hx = aabb[3], hy = aabb[4], hz = aabb[5];

    // robust slab intersection (matches reference: where(|d|<1e-10, 1e-10, d))
    const float sdx = (fabsf(dx) < 1e-10f) ? 1e-10f : dx;
    const float sdy = (fabsf(dy) < 1e-10f) ? 1e-10f : dy;
    const float sdz = (fabsf(dz) < 1e-10f) ? 1e-10f : dz;
    const float ivx = 1.0f / sdx, ivy = 1.0f / sdy, ivz = 1.0f / sdz;
    const float t0x = (lx - ox) * ivx, t1x = (hx - ox) * ivx;
    const float t0y = (ly - oy) * ivy, t1y = (hy - oy) * ivy;
    const float t0z = (lz - oz) * ivz, t1z = (hz - oz) * ivz;
    float tmin = fmaxf(fmaxf(fminf(t0x, t1x), fminf(t0y, t1y)), fminf(t0z, t1z));
    float tmax = fminf(fminf(fmaxf(t0x, t1x), fmaxf(t0y, t1y)), fmaxf(t0z, t1z));
    tmin = fmaxf(tmin, 0.0f);   // NEAR = 0

    const float t_start = tmin + (float)j * STEP;
    const float t_end   = t_start + STEP;
    const float t_mid   = 0.5f * (t_start + t_end);

    const float px = ox + dx * t_mid;
    const float py = oy + dy * t_mid;
    const float pz = oz + dz * t_mid;

    const float ux = (px - lx) / (hx - lx);
    const float uy = (py - ly) / (hy - ly);
    const float uz = (pz - lz) / (hz - lz);

    int ix = (int)floorf(ux * (float)RES);
    int iy = (int)floorf(uy * (float)RES);
    int iz = (int)floorf(uz * (float)RES);
    ix = min(max(ix, 0), RES - 1);
    iy = min(max(iy, 0), RES - 1);
    iz = min(max(iz, 0), RES - 1);

    const float occ = occs[((size_t)ix * RES + iy) * RES + iz];

    const bool inside = (ux >= 0.0f) & (ux < 1.0f) &
                        (uy >= 0.0f) & (uy < 1.0f) &
                        (uz >= 0.0f) & (uz < 1.0f);
    const float alpha = 1.0f - expf(-occ * STEP);
    const bool mask = inside & (t_end <= tmax) & (alpha > ALPHA_THRE) & (tmax > tmin);
    const float m = mask ? 1.0f : 0.0f;

    const size_t NS = (size_t)N * NSTEPS;
    const size_t base = (size_t)r * NSTEPS + (size_t)j;

    // positions [N,S,3] — 12 B/lane contiguous per wave
    out[base * 3 + 0] = px * m;
    out[base * 3 + 1] = py * m;
    out[base * 3 + 2] = pz * m;
    // t_starts / t_ends / ray_indices(as float) / mask(as float)
    out[NS * 3 + base] = t_start * m;
    out[NS * 4 + base] = t_end * m;
    out[NS * 5 + base] = mask ? (float)r : -1.0f;
    out[NS * 6 + base] = m;
}

extern "C" void kernel_launch(void* const* d_in, const int* in_sizes, int n_in,
                              void* d_out, int out_size, void* d_ws, size_t ws_size,
                              hipStream_t stream) {
    const float* origins = (const float*)d_in[0];
    const float* dirs    = (const float*)d_in[1];
    const float* occs    = (const float*)d_in[2];
    const float* aabb    = (const float*)d_in[3];
    float* out = (float*)d_out;

    const int N = in_sizes[0] / 3;   // 16384

    nerfacc_sampler_kernel<<<dim3(N), dim3(NSTEPS), 0, stream>>>(
        origins, dirs, occs, aabb, out, N);
}